// Round 10
// baseline (3708.600 us; speedup 1.0000x reference)
//
#include <hip/hip_runtime.h>
#include <hip/hip_bf16.h>

typedef __hip_bfloat16 bf16;

#define NN 192      // nodes per group
#define NG 8        // groups
#define BB 1536     // batch
#define EHID 256
#define DH 320      // decoder hidden
#define PRED 12
#define TRI ((NN*(NN+1))/2)   // 18528 packed lower-triangle elements

__device__ __forceinline__ float waveSum(float v){
#pragma unroll
  for (int o = 32; o > 0; o >>= 1) v += __shfl_down(v, o);
  return v;
}
__device__ __forceinline__ double waveSumD(double v){
#pragma unroll
  for (int o = 32; o > 0; o >>= 1) v += __shfl_down(v, o);
  return v;
}

__device__ __forceinline__ double blockSumD(double v, double* red){
  int lane = threadIdx.x & 63, wid = threadIdx.x >> 6, nw = (int)blockDim.x >> 6;
  double s = waveSumD(v);
  __syncthreads();
  if (lane == 0) red[wid] = s;
  __syncthreads();
  if (wid == 0){
    double t = (lane < nw) ? red[lane] : 0.0;
    t = waveSumD(t);
    if (lane == 0) red[0] = t;
  }
  __syncthreads();
  return red[0];
}

// ---------------- dtype probe + conversion ----------------

__global__ void k_zero_int(int* __restrict__ p, int n){
  int i = blockIdx.x*blockDim.x + threadIdx.x;
  if (i < n) p[i] = 0;
}
__global__ void k_zero_f(float* __restrict__ p, int n){
  int i = blockIdx.x*blockDim.x + threadIdx.x;
  if (i < n) p[i] = 0.f;
}

__global__ void k_probe(const unsigned short* __restrict__ src, int n, int* __restrict__ cnt){
  int tid = blockIdx.x*blockDim.x + threadIdx.x;
  int stride = gridDim.x*blockDim.x;
  int bad = 0;
  for (int j = tid; j < n; j += stride){
    float v = __uint_as_float(((unsigned int)src[j]) << 16);
    if (!(fabsf(v) < 100.f)) bad++;
  }
#pragma unroll
  for (int o = 32; o > 0; o >>= 1) bad += __shfl_down(bad, o);
  if ((threadIdx.x & 63) == 0 && bad > 0) atomicAdd(cnt, bad);
}
__global__ void k_flag(const int* __restrict__ cnt, int* __restrict__ flag){
  *flag = (*cnt > 4096) ? 1 : 0;        // 1 = inputs are fp32, 0 = bf16
}

struct CvtArgs {
  const void* src[20];
  float*      dst[20];
  int         n[20];
};

__global__ void k_convert(CvtArgs a, const int* __restrict__ flag){
  int id = blockIdx.y;
  int n = a.n[id];
  float* d = a.dst[id];
  int t = blockIdx.x*blockDim.x + threadIdx.x;
  int stride = gridDim.x*blockDim.x;
  if (*flag == 0){
    const bf16* s = (const bf16*)a.src[id];
    for (int j = t; j < n; j += stride) d[j] = __bfloat162float(s[j]);
  } else {
    const float* s = (const float*)a.src[id];
    for (int j = t; j < n; j += stride) d[j] = s[j];
  }
}

// ---------------- elementwise / small kernels ----------------

__global__ void k_embed(const float* __restrict__ in, const float* __restrict__ W,
                        const float* __restrict__ b, float* __restrict__ out){
  int r = blockIdx.x, e = threadIdx.x;
  float x = in[r*2], y = in[r*2+1];
  float v = W[e*2]*x + W[e*2+1]*y + b[e];
  out[r*64+e] = v > 0.f ? v : 0.f;
}

__global__ void k_concat(const float* __restrict__ henc, const float* __restrict__ z,
                         float* __restrict__ h){
  int idx = blockIdx.x*blockDim.x + threadIdx.x;
  if (idx >= BB*DH) return;
  int b = idx / DH, j = idx - b*DH;
  h[idx] = (j < EHID) ? henc[b*EHID + j] : z[(b/NN)*64 + (j - EHID)];
}

__global__ void k_copy_f(const float* __restrict__ in, float* __restrict__ dst, int n){
  int i = blockIdx.x*blockDim.x + threadIdx.x;
  if (i < n) dst[i] = in[i];
}

// gates = A1@W1^T + A2@W2^T + b1 + b2 ; M=1536, N,K multiples of 32/64
__global__ __launch_bounds__(256) void k_gates(
    const float* __restrict__ A1, const float* __restrict__ W1, int K1,
    const float* __restrict__ A2, const float* __restrict__ W2, int K2,
    const float* __restrict__ b1, const float* __restrict__ b2,
    float* __restrict__ C, int N){
  __shared__ __align__(16) float As[32][68];
  __shared__ __align__(16) float Ws[32][68];
  int tid = threadIdx.x;
  int tx = tid & 15, ty = tid >> 4;
  int n0 = blockIdx.x * 64, m0 = blockIdx.y * 64;
  float acc[4][4] = {};
  for (int ph = 0; ph < 2; ++ph){
    const float* A = ph ? A2 : A1;
    const float* W = ph ? W2 : W1;
    int K = ph ? K2 : K1;
    for (int k0 = 0; k0 < K; k0 += 32){
      {
        int am = tid >> 2, ak = (tid & 3) * 8;
        const float* srcA = A + (size_t)(m0+am)*K + k0 + ak;
        float4 f0 = *(const float4*)(srcA);
        float4 f1 = *(const float4*)(srcA+4);
        As[ak+0][am]=f0.x; As[ak+1][am]=f0.y; As[ak+2][am]=f0.z; As[ak+3][am]=f0.w;
        As[ak+4][am]=f1.x; As[ak+5][am]=f1.y; As[ak+6][am]=f1.z; As[ak+7][am]=f1.w;
        const float* srcW = W + (size_t)(n0+am)*K + k0 + ak;
        float4 w0 = *(const float4*)(srcW);
        float4 w1 = *(const float4*)(srcW+4);
        Ws[ak+0][am]=w0.x; Ws[ak+1][am]=w0.y; Ws[ak+2][am]=w0.z; Ws[ak+3][am]=w0.w;
        Ws[ak+4][am]=w1.x; Ws[ak+5][am]=w1.y; Ws[ak+6][am]=w1.z; Ws[ak+7][am]=w1.w;
      }
      __syncthreads();
#pragma unroll
      for (int k = 0; k < 32; ++k){
        float4 a0 = *(const float4*)&As[k][ty*4];
        float4 b0 = *(const float4*)&Ws[k][tx*4];
        float av[4] = {a0.x, a0.y, a0.z, a0.w};
        float bv[4] = {b0.x, b0.y, b0.z, b0.w};
#pragma unroll
        for (int i = 0; i < 4; ++i)
#pragma unroll
          for (int j = 0; j < 4; ++j)
            acc[i][j] += av[i]*bv[j];
      }
      __syncthreads();
    }
  }
  float bs[4];
#pragma unroll
  for (int j = 0; j < 4; ++j){
    int col = n0 + tx*4 + j;
    bs[j] = b1[col] + b2[col];
  }
#pragma unroll
  for (int i = 0; i < 4; ++i){
    int row = m0 + ty*4 + i;
    float4 v;
    v.x = acc[i][0] + bs[0]; v.y = acc[i][1] + bs[1];
    v.z = acc[i][2] + bs[2]; v.w = acc[i][3] + bs[3];
    *(float4*)&C[(size_t)row*N + n0 + tx*4] = v;
  }
}

__global__ void k_lstm(const float* __restrict__ gates, float* __restrict__ c,
                       float* __restrict__ h, int H){
  int idx = blockIdx.x*blockDim.x + threadIdx.x;
  if (idx >= BB*H) return;
  int b = idx / H, j = idx - b*H;
  const float* g = gates + (size_t)b*4*H;
  float gi = g[j], gf = g[H+j], gg = g[2*H+j], go = g[3*H+j];
  float si = 1.f/(1.f+expf(-gi));
  float sf = 1.f/(1.f+expf(-gf));
  float so = 1.f/(1.f+expf(-go));
  float cc = sf*c[idx] + si*tanhf(gg);
  c[idx] = cc;
  h[idx] = so*tanhf(cc);
}

// h(1536x320) -> traj(1536x2) fp32 + output slice `step` (fp32 or bf16 per flag)
__global__ void k_outproj(const float* __restrict__ h, const float* __restrict__ W,
                          const float* __restrict__ bo, float* __restrict__ traj,
                          void* __restrict__ outbase, int step, const int* __restrict__ flag){
  int b = blockIdx.x, lane = threadIdx.x;
  const float* hb = h + (size_t)b*DH;
  float a0 = 0.f, a1 = 0.f;
  for (int k = lane; k < DH; k += 64){
    float hv = hb[k];
    a0 += hv*W[k];
    a1 += hv*W[DH+k];
  }
  a0 = waveSum(a0); a1 = waveSum(a1);
  if (lane == 0){
    a0 += bo[0]; a1 += bo[1];
    traj[b*2] = a0; traj[b*2+1] = a1;
    size_t idx = (size_t)step*BB*2 + (size_t)b*2;
    if (*flag == 0){
      bf16* o = (bf16*)outbase;
      o[idx] = __float2bfloat16(a0); o[idx+1] = __float2bfloat16(a1);
    } else {
      float* o = (float*)outbase;
      o[idx] = a0; o[idx+1] = a1;
    }
  }
}

// ---------------- signed-graph kernels (fp64 numeric path) ----------------

__global__ void k_sg_emb(const float* __restrict__ h, const float* __restrict__ Wne,
                         const float* __restrict__ bne, const float* __restrict__ Watt,
                         double* __restrict__ sself, double* __restrict__ sother){
  int node = blockIdx.x, e = threadIdx.x;
  const float* hb = h + (size_t)node*DH;
  double acc = (double)bne[e];
  for (int k = 0; k < DH; ++k) acc += (double)hb[k]*(double)Wne[e*DH+k];
  double po = acc * (double)Watt[e];       // a_other = W_att[0, :64]
  double ps = acc * (double)Watt[64+e];    // a_self  = W_att[0, 64:]
  po = waveSumD(po); ps = waveSumD(ps);
  if (e == 0){ sother[node] = po; sself[node] = ps; }
}

__global__ void k_sg_edgecol(const double* __restrict__ sself, const double* __restrict__ sother,
                             const float* __restrict__ batt, double* __restrict__ edge){
  int g = blockIdx.x, j = threadIdx.x;
  const double* ss = sself + g*NN;
  double bb = (double)batt[0];
  double sj = sother[g*NN + j];
  double m = -1e300;
  for (int i = 0; i < NN; ++i){
    double e = ss[i] + sj + bb; e = e > 0.0 ? e : 0.2*e;
    m = fmax(m, e);
  }
  double sum = 0.0;
  for (int i = 0; i < NN; ++i){
    double e = ss[i] + sj + bb; e = e > 0.0 ? e : 0.2*e;
    sum += exp(e - m);
  }
  double* E = edge + (size_t)g*NN*NN;
  for (int i = 0; i < NN; ++i){
    double e = ss[i] + sj + bb; e = e > 0.0 ? e : 0.2*e;
    E[i*NN + j] = exp(e - m)/sum;
  }
}

__global__ void k_sg_sym(const double* __restrict__ edge, double* __restrict__ esym){
  int idx = blockIdx.x*blockDim.x + threadIdx.x;
  if (idx >= NG*NN*NN) return;
  int g = idx / (NN*NN), r = idx - g*NN*NN;
  int i = r / NN, j = r - i*NN;
  const double* E = edge + (size_t)g*NN*NN;
  esym[idx] = (i <= j) ? E[i*NN + j] : E[j*NN + i];
}

__global__ void k_sg_dsum(const double* __restrict__ esym, double* __restrict__ darr){
  int i = blockIdx.x*blockDim.x + threadIdx.x;
  if (i >= NG*NN) return;
  int g = i / NN, li = i - g*NN;
  const double* E = esym + (size_t)g*NN*NN + (size_t)li*NN;
  double s = 0.0;
  for (int j = 0; j < NN; ++j) s += E[j];
  darr[i] = fmax(s, 1e-300);
}

// packed lower-triangle L_sym
__global__ void k_sg_lsym(const double* __restrict__ esym, const double* __restrict__ darr,
                          double* __restrict__ Lpack){
  int idx = blockIdx.x*blockDim.x + threadIdx.x;
  if (idx >= NG*NN*NN) return;
  int g = idx / (NN*NN), r = idx - g*NN*NN;
  int i = r / NN, j = r - i*NN;
  if (j > i) return;
  double w = esym[idx];
  double lij = (i == j) ? (darr[g*NN+i] - w) : (-w);
  Lpack[(size_t)g*TRI + i*(i+1)/2 + j] = lij / (sqrt(darr[g*NN+i])*sqrt(darr[g*NN+j]));
}

// LDS-resident packed-symmetric Householder tridiag, 1024 threads (16 waves),
// TWO barriers per step (fused vtp / inline-w / pipelined next-column+sigma),
// 4-row-batched wave-per-row matvec. + Sturm bisection + inverse iteration +
// paired back-transform + Gram-Schmidt vs v0=sqrt(d).
// dynamic LDS = (TRI + 9*NN + 48)*8 = 162432 B.
__global__ __launch_bounds__(1024) void k_sg_eigen(const double* __restrict__ Lpack,
                                                   const double* __restrict__ darr,
                                                   double* __restrict__ v1out){
  extern __shared__ double lds[];
  double* tri   = lds;                 // TRI
  double* vb0   = lds + TRI;           // NN  (column double-buffer A)
  double* vb1   = vb0 + NN;            // NN  (column double-buffer B)
  double* p     = vb1 + NN;            // NN
  double* dd    = p + NN;              // NN
  double* ee    = dd + NN;             // NN
  double* yv    = ee + NN;             // NN
  double* lu_d  = yv + NN;             // NN
  double* lu_du = lu_d + NN;           // NN
  double* lu_du2= lu_du + NN;          // NN
  double* redA  = lu_du2 + NN;         // 16
  double* redB  = redA + 16;           // 16
  double* redC  = redB + 16;           // 16
  double* lu_dl = vb0;                 // alias: vb0 dead in LU phase
  int*    lu_piv= (int*)p;             // alias: p dead in LU phase

  int g = blockIdx.x, tid = threadIdx.x;
  int lane = tid & 63, wid = tid >> 6;  // 16 waves

  const double* src = Lpack + (size_t)g*TRI;
  for (int t = tid; t < TRI; t += 1024) tri[t] = src[t];
  __syncthreads();

  // ---- Phase A (k=0 only): load column 0 into vb0, sigma partials -> redA ----
  {
    double part = 0.0;
    if (tid < NN-1){
      int i = 1+tid;
      double x = tri[(i*(i+1))>>1];      // element (i,0)
      vb0[i] = x;
      if (i > 1) part = x*x;
    }
    part = waveSumD(part);
    if (lane == 0) redA[wid] = part;
    __syncthreads();
  }

  // ---- tridiagonalization: 2 barriers per step ----
  for (int k = 0; k < NN-2; ++k){
    double* vcur = (k & 1) ? vb1 : vb0;
    double* vnxt = (k & 1) ? vb0 : vb1;
    int m = NN-1-k;                      // trailing rows i = k+1..NN-1
    double sigma = 0.0;
#pragma unroll
    for (int w = 0; w < 16; ++w) sigma += redA[w];
    double alpha = vcur[k+1];
    double beta, tau, scale;
    if (sigma <= 1e-280){ tau = 0.0; beta = alpha; scale = 0.0; }
    else {
      beta = -copysign(sqrt(alpha*alpha + sigma), alpha);
      tau = (beta - alpha)/beta;
      scale = 1.0/(alpha - beta);
    }
    if (tid == 0){
      int dk = (k*(k+1))>>1; dk += k;
      dd[k] = tri[dk]; ee[k] = beta;
      tri[dk] = tau;                     // stash tau on dead diagonal slot
    }
    // store scaled u into dead sub-column k (for back-transform)
    if (tid < m-1){
      int i = k+2+tid;
      tri[((i*(i+1))>>1) + k] = vcur[i]*scale;
    }
    // matvec: 4-row-batched wave-per-row; fused u^T p partials
    double vtp_part = 0.0;
    for (int base = 0; base < m; base += 64){
      int r0 = base + wid;
      int i0 = k+1+r0, i1 = i0+16, i2 = i0+32, i3 = i0+48;
      bool c0 = r0 < m, c1 = r0+16 < m, c2 = r0+32 < m, c3 = r0+48 < m;
      int bi0 = c0 ? ((i0*(i0+1))>>1) : 0;
      int bi1 = c1 ? ((i1*(i1+1))>>1) : 0;
      int bi2 = c2 ? ((i2*(i2+1))>>1) : 0;
      int bi3 = c3 ? ((i3*(i3+1))>>1) : 0;
      double s0=0.0, s1=0.0, s2=0.0, s3=0.0;
      for (int j = k+2+lane; j < NN; j += 64){
        double vj = vcur[j];
        int cj = (j*(j+1))>>1;
        if (c0){ double A = (j <= i0) ? tri[bi0+j] : tri[cj+i0]; s0 += A*vj; }
        if (c1){ double A = (j <= i1) ? tri[bi1+j] : tri[cj+i1]; s1 += A*vj; }
        if (c2){ double A = (j <= i2) ? tri[bi2+j] : tri[cj+i2]; s2 += A*vj; }
        if (c3){ double A = (j <= i3) ? tri[bi3+j] : tri[cj+i3]; s3 += A*vj; }
      }
#pragma unroll
      for (int o = 32; o > 0; o >>= 1){
        s0 += __shfl_down(s0, o); s1 += __shfl_down(s1, o);
        s2 += __shfl_down(s2, o); s3 += __shfl_down(s3, o);
      }
      if (lane == 0){
        if (c0){ double pi = tau*(tri[bi0 + k+1] + scale*s0); p[i0] = pi;
                 double ui = (i0 == k+1) ? 1.0 : vcur[i0]*scale; vtp_part += ui*pi; }
        if (c1){ double pi = tau*(tri[bi1 + k+1] + scale*s1); p[i1] = pi;
                 double ui = vcur[i1]*scale; vtp_part += ui*pi; }
        if (c2){ double pi = tau*(tri[bi2 + k+1] + scale*s2); p[i2] = pi;
                 double ui = vcur[i2]*scale; vtp_part += ui*pi; }
        if (c3){ double pi = tau*(tri[bi3 + k+1] + scale*s3); p[i3] = pi;
                 double ui = vcur[i3]*scale; vtp_part += ui*pi; }
      }
    }
    if (lane == 0) redB[wid] = vtp_part;
    __syncthreads();                     // B2: p + vtp partials complete
    double vtp = 0.0;
#pragma unroll
    for (int w = 0; w < 16; ++w) vtp += redB[w];
    double Kc = 0.5*tau*vtp;
    // rank-2 update with inline w; extract next column + sigma on the fly
    double sig_part = 0.0;
    int half = (m+1) >> 1;
    for (int r = wid; r < half; r += 16){
#pragma unroll 1
      for (int sel = 0; sel < 2; ++sel){
        int rr = sel ? (m-1-r) : r;
        if (sel && rr == r) break;
        int i = k+1+rr, bi = (i*(i+1))>>1;
        double ui = (rr == 0) ? 1.0 : vcur[i]*scale;
        double wi = p[i] - Kc*ui;
        for (int j = k+1+lane; j <= i; j += 64){
          double uj = (j == k+1) ? 1.0 : vcur[j]*scale;
          double wj = p[j] - Kc*uj;
          double nv = tri[bi+j] - (ui*wj + wi*uj);
          tri[bi+j] = nv;
          if (j == k+1 && i >= k+2){     // lane 0 owns j==k+1
            vnxt[i] = nv;
            if (i >= k+3) sig_part += nv*nv;
          }
        }
      }
    }
    if (lane == 0) redA[wid] = sig_part; // next step's sigma partials
    __syncthreads();                     // B3 (doubles as next step's B1)
  }
  if (tid == 0){
    dd[NN-2] = tri[((NN-2)*(NN-1))/2 + (NN-2)];
    ee[NN-2] = tri[((NN-1)*NN)/2 + (NN-2)];
    dd[NN-1] = tri[((NN-1)*NN)/2 + (NN-1)];
  }
  __syncthreads();

  // ---- bisection (wave 0) + serial LU/inverse-iteration (lane 0) ----
  if (wid == 0){
    double mn = 1e300, mx = -1e300;
    for (int i = lane; i < NN; i += 64){
      double r = (i > 0 ? fabs(ee[i-1]) : 0.0) + (i < NN-1 ? fabs(ee[i]) : 0.0);
      mn = fmin(mn, dd[i]-r); mx = fmax(mx, dd[i]+r);
    }
#pragma unroll
    for (int o = 32; o > 0; o >>= 1){
      mn = fmin(mn, __shfl_down(mn, o));
      mx = fmax(mx, __shfl_down(mx, o));
    }
    mn = __shfl(mn, 0); mx = __shfl(mx, 0);
    double lo = mn - 1e-8 - 1e-9*fabs(mn);
    double hi = mx + 1e-8 + 1e-9*fabs(mx);
    for (int it = 0; it < 10; ++it){
      double lam = lo + (hi-lo)*((double)(lane+1)/65.0);
      int cnt = 0;
      double q = dd[0] - lam;
      if (q < 0.0) cnt++;
      for (int i2 = 1; i2 < NN; ++i2){
        double den = q;
        if (fabs(den) < 1e-280) den = (den < 0.0) ? -1e-280 : 1e-280;
        q = dd[i2] - lam - ee[i2-1]*ee[i2-1]/den;
        if (q < 0.0) cnt++;
      }
      unsigned long long bal = __ballot(cnt >= 2);
      if (bal == 0ull){
        lo = lo + (hi-lo)*(64.0/65.0);
      } else {
        int j0 = __ffsll(bal) - 1;
        double nl = lo + (hi-lo)*((double)j0/65.0);
        double nh = lo + (hi-lo)*((double)(j0+1)/65.0);
        lo = nl; hi = nh;
      }
    }
    double lam1 = 0.5*(lo+hi);

    if (lane == 0){
      for (int i = 0; i < NN; ++i) lu_d[i] = dd[i] - lam1;
      for (int i = 0; i < NN-1; ++i){ lu_dl[i] = ee[i]; lu_du[i] = ee[i]; }
      for (int i = 0; i < NN-2; ++i) lu_du2[i] = 0.0;
      for (int i = 0; i < NN-1; ++i){
        if (fabs(lu_d[i]) >= fabs(lu_dl[i])){
          double di = lu_d[i];
          if (fabs(di) < 1e-30){ di = (di < 0.0) ? -1e-30 : 1e-30; lu_d[i] = di; }
          double fact = lu_dl[i]/di;
          lu_dl[i] = fact;
          lu_d[i+1] -= fact*lu_du[i];
          lu_piv[i] = 0;
        } else {
          double fact = lu_d[i]/lu_dl[i];
          lu_d[i] = lu_dl[i];
          double tmp = lu_d[i+1];
          lu_d[i+1] = lu_du[i] - fact*tmp;
          if (i < NN-2){ lu_du2[i] = lu_du[i+1]; lu_du[i+1] = -fact*lu_du[i+1]; }
          lu_du[i] = tmp;
          lu_dl[i] = fact;
          lu_piv[i] = 1;
        }
      }
      if (fabs(lu_d[NN-1]) < 1e-30)
        lu_d[NN-1] = (lu_d[NN-1] < 0.0) ? -1e-30 : 1e-30;
      for (int i = 0; i < NN; ++i) yv[i] = 1.0 + 0.001*(double)((i*37)%29);
      for (int round = 0; round < 2; ++round){
        for (int i = 0; i < NN-1; ++i){
          if (lu_piv[i] == 0){
            yv[i+1] -= lu_dl[i]*yv[i];
          } else {
            double t = yv[i]; yv[i] = yv[i+1]; yv[i+1] = t - lu_dl[i]*yv[i];
          }
        }
        double mx1 = 0.0;
        for (int i = 0; i < NN; ++i) mx1 = fmax(mx1, fabs(yv[i]));
        double inv1 = (mx1 > 0.0 && isfinite(mx1)) ? 1.0/mx1 : 1.0;
        for (int i = 0; i < NN; ++i) yv[i] *= inv1;
        yv[NN-1] = yv[NN-1]/lu_d[NN-1];
        yv[NN-2] = (yv[NN-2] - lu_du[NN-2]*yv[NN-1])/lu_d[NN-2];
        for (int i = NN-3; i >= 0; --i)
          yv[i] = (yv[i] - lu_du[i]*yv[i+1] - lu_du2[i]*yv[i+2])/lu_d[i];
        double mxv = 0.0;
        for (int i = 0; i < NN; ++i) mxv = fmax(mxv, fabs(yv[i]));
        double inv = (mxv > 0.0 && isfinite(mxv)) ? 1.0/mxv : 1.0;
        for (int i = 0; i < NN; ++i){
          double val = yv[i]*inv;
          if (!isfinite(val)) val = 0.0;
          yv[i] = val;
        }
      }
    }
  }
  __syncthreads();                       // yv ready

  // ---- back-transform, reflectors applied in PAIRS (95 pairs) ----
  // y <- H_{k2-1} H_{k2} y : a=u2^T y, b=u1^T y, c=u1^T u2;
  // y -= t2*a*u2 + t1*(b - t2*a*c)*u1
  for (int k2 = NN-3; k2 >= 1; k2 -= 2){
    int k1 = k2-1;
    double t2 = tri[((k2*(k2+1))>>1) + k2];
    double t1 = tri[((k1*(k1+1))>>1) + k1];
    int m2 = NN - k2;                    // i in [k2, NN)
    double pa = 0.0, pb = 0.0, pc = 0.0;
    double u1v = 0.0, u2v = 0.0;
    if (tid < m2){
      int i = k2 + tid;
      int bi = (i*(i+1))>>1;
      u1v = (i == k2) ? 1.0 : tri[bi + k1];
      u2v = (i == k2) ? 0.0 : ((i == k2+1) ? 1.0 : tri[bi + k2]);
      double y = yv[i];
      pa = u2v*y; pb = u1v*y; pc = u1v*u2v;
    }
    pa = waveSumD(pa); pb = waveSumD(pb); pc = waveSumD(pc);
    if (lane == 0){ redA[wid] = pa; redB[wid] = pb; redC[wid] = pc; }
    __syncthreads();
    double a = 0.0, b = 0.0, c = 0.0;
#pragma unroll
    for (int w = 0; w < 16; ++w){ a += redA[w]; b += redB[w]; c += redC[w]; }
    double ca = t2*a;
    double cb = t1*(b - ca*c);
    if (tid < m2){
      int i = k2 + tid;
      yv[i] -= ca*u2v + cb*u1v;
    }
    __syncthreads();
  }

  // ---- Gram-Schmidt against v0 = sqrt(d) + normalize ----
  {
    double pd = 0.0, pn2 = 0.0;
    if (tid < NN){
      double sd = sqrt(darr[g*NN + tid]);
      pd = sd*yv[tid];
      pn2 = darr[g*NN + tid];
    }
    pd = waveSumD(pd); pn2 = waveSumD(pn2);
    if (lane == 0){ redA[wid] = pd; redB[wid] = pn2; }
    __syncthreads();
    double dot = 0.0, n2 = 0.0;
#pragma unroll
    for (int w = 0; w < 16; ++w){ dot += redA[w]; n2 += redB[w]; }
    double coef = dot/fmax(n2, 1e-300);
    if (tid < NN) yv[tid] -= coef*sqrt(darr[g*NN + tid]);
    __syncthreads();
    double pn = 0.0;
    if (tid < NN) pn = yv[tid]*yv[tid];
    pn = waveSumD(pn);
    if (lane == 0) redA[wid] = pn;
    __syncthreads();
    double s2 = 0.0;
#pragma unroll
    for (int w = 0; w < 16; ++w) s2 += redA[w];
    double nrm = sqrt(s2);
    double inv = (nrm > 0.0 && isfinite(nrm)) ? 1.0/nrm : 0.0;
    if (tid < NN){
      double val = yv[tid]*inv;
      if (!isfinite(val)) val = 0.0;
      v1out[g*NN + tid] = val;
    }
  }
}

// kmeans on row-normalized [sqrt(d)/||.||, v1]  (fp64)
__global__ __launch_bounds__(256) void k_sg_kmeans(const double* __restrict__ darr,
                                                   const double* __restrict__ v1,
                                                   int* __restrict__ labels){
  __shared__ double px[NN], py[NN], cx[96], cy[96];
  __shared__ int lab[NN];
  __shared__ double red[16];
  int g = blockIdx.x, tid = threadIdx.x;
  double part = 0.0;
  for (int i = tid; i < NN; i += 256) part += darr[g*NN + i];
  double sumd = blockSumD(part, red);
  double invn = 1.0/sqrt(fmax(sumd, 1e-300));
  for (int i = tid; i < NN; i += 256){
    double h0 = sqrt(darr[g*NN + i])*invn;
    double h1 = v1[g*NN + i];
    double rn = sqrt(h0*h0 + h1*h1);
    double ax = h0/rn, ay = h1/rn;
    if (!isfinite(ax)) ax = 0.0;
    if (!isfinite(ay)) ay = 0.0;
    px[i] = ax; py[i] = ay;
  }
  __syncthreads();
  if (tid < 96){ cx[tid] = px[tid]; cy[tid] = py[tid]; }
  __syncthreads();
  for (int it = 0; it <= 10; ++it){
    if (tid < NN){
      double bx = px[tid], by = py[tid];
      double best = 1e300; int bi = 0;
      for (int a = 0; a < 96; ++a){
        double dx = bx - cx[a], dy = by - cy[a];
        double d2 = dx*dx + dy*dy;
        if (d2 < best){ best = d2; bi = a; }
      }
      lab[tid] = bi;
    }
    __syncthreads();
    if (it == 10) break;
    if (tid < 96){
      int c = 0; double sx = 0.0, sy = 0.0;
      for (int i = 0; i < NN; ++i){
        if (lab[i] == tid){ c++; sx += px[i]; sy += py[i]; }
      }
      if (c > 0){ cx[tid] = sx/(double)c; cy[tid] = sy/(double)c; }
      else      { cx[tid] = px[tid];      cy[tid] = py[tid]; }
    }
    __syncthreads();
  }
  if (tid < NN) labels[g*NN + tid] = lab[tid];
}

// S = pos_alpha + neg_alpha (fp64 in, fp32 out)
__global__ void k_sg_alpha(const double* __restrict__ esym, const int* __restrict__ labels,
                           float* __restrict__ S){
  __shared__ int lbs[NN];
  int g = blockIdx.x, j = threadIdx.x;
  if (j < NN) lbs[j] = labels[g*NN + j];
  __syncthreads();
  const double* E = esym + (size_t)g*NN*NN;
  const double NEG = -100000000.0;
  int lj = lbs[j];
  double mp = -1e300, mn = -1e300;
  for (int i = 0; i < NN; ++i){
    double w = E[i*NN + j];
    bool sm = (lbs[i] == lj);
    double vp = sm ? w : w*NEG; vp = vp > 0.0 ? vp : 0.2*vp;
    double vn = sm ? w*NEG : w; vn = vn > 0.0 ? vn : 0.2*vn;
    mp = fmax(mp, vp); mn = fmax(mn, vn);
  }
  double sp = 0.0, sn = 0.0;
  for (int i = 0; i < NN; ++i){
    double w = E[i*NN + j];
    bool sm = (lbs[i] == lj);
    double vp = sm ? w : w*NEG; vp = vp > 0.0 ? vp : 0.2*vp;
    double vn = sm ? w*NEG : w; vn = vn > 0.0 ? vn : 0.2*vn;
    sp += exp(vp - mp); sn += exp(vn - mn);
  }
  float* So = S + (size_t)g*NN*NN;
  for (int i = 0; i < NN; ++i){
    double w = E[i*NN + j];
    bool sm = (lbs[i] == lj);
    double vp = sm ? w : w*NEG; vp = vp > 0.0 ? vp : 0.2*vp;
    double vn = sm ? w*NEG : w; vn = vn > 0.0 ? vn : 0.2*vn;
    So[i*NN + j] = (float)(exp(vp - mp)/sp + exp(vn - mn)/sn);
  }
}

// h_out[i,:] = sum_j S[i,j] * relu(h_in[j,:]) per group
__global__ __launch_bounds__(320) void k_sg_feat(const float* __restrict__ S,
                                                 const float* __restrict__ hin,
                                                 float* __restrict__ hout){
  int r = blockIdx.x;
  int g = r / NN, li = r - g*NN;
  int dh = threadIdx.x;
  const float* Srow = S + (size_t)g*NN*NN + (size_t)li*NN;
  const float* hb = hin + (size_t)g*NN*DH;
  float acc = 0.f;
  for (int j = 0; j < NN; ++j){
    float w = Srow[j];
    float x = hb[(size_t)j*DH + dh];
    acc += w*(x > 0.f ? x : 0.f);
  }
  hout[(size_t)r*DH + dh] = acc;
}

// ---------------- host ----------------

extern "C" void kernel_launch(void* const* d_in, const int* in_sizes, int n_in,
                              void* d_out, int out_size, void* d_ws, size_t ws_size,
                              hipStream_t stream){
  (void)n_in; (void)out_size; (void)ws_size;

  // ---- workspace layout (float offsets) ----
  float* ws = (float*)d_ws;
  float* inp   = ws;                       // 98304
  float* gates = ws + 98304;               // 1966080
  float* hA    = ws + 2064384;             // 491520
  float* hB    = ws + 2555904;             // 491520
  float* cD    = ws + 3047424;             // 491520
  float* traj  = ws + 3538944;             // 3072
  double* sself_d  = (double*)(ws + 3542016);  // 3072 f
  double* sother_d = (double*)(ws + 3545088);  // 3072 f
  double* darr_d   = (double*)(ws + 3548160);  // 3072 f
  double* v1_d     = (double*)(ws + 3551232);  // 3072 f
  int*    labels   = (int*)(ws + 3554304);     // 1536
  // fp64 graph matrices overlay the (dead) gates buffer:
  double* edge_d = (double*)gates;             // 589824 f
  double* esym_d = (double*)(gates + 589824);  // 589824 f
  double* Lpack  = (double*)(gates + 1179648); // packed: NG*TRI dbl = 296448 f
  float*  Smat   = gates;                      // fp32 S reuses edge_d space (dead by then)
  // fp32 parameter arena:
  float* a_traj = ws + 3555840;            // 61440
  float* a_z    = ws + 3617280;            // 512
  float* a_Wemb = ws + 3617792;            // 128
  float* a_bemb = ws + 3617920;            // 64
  float* a_Wihe = ws + 3617984;            // 65536
  float* a_Whhe = ws + 3683520;            // 262144
  float* a_bihe = ws + 3945664;            // 1024
  float* a_bhhe = ws + 3946688;            // 1024
  float* a_Wihd = ws + 3947712;            // 81920
  float* a_Whhd = ws + 4029632;            // 409600
  float* a_bihd = ws + 4439232;            // 1280
  float* a_bhhd = ws + 4440512;            // 1280
  float* a_Wout = ws + 4441792;            // 640
  float* a_bout = ws + 4442432;            // 64
  float* a_Wne  = ws + 4442496;            // 20480
  float* a_bne  = ws + 4462976;            // 64
  float* a_Watt = ws + 4463040;            // 128
  float* a_batt = ws + 4463168;            // 64
  int* cnt  = (int*)(ws + 4463232);
  int* flag = (int*)(ws + 4463233);        // ~17.0 MiB total

  // allow >64KB dynamic LDS for the eigen kernel (idempotent, host-side)
  const int EIG_LDS = (int)((TRI + 9*NN + 48) * sizeof(double));   // 162432
  hipFuncSetAttribute((const void*)k_sg_eigen,
                      hipFuncAttributeMaxDynamicSharedMemorySize, EIG_LDS);

  // ---- dtype probe ----
  k_zero_int<<<1, 64, 0, stream>>>(cnt, 2);
  k_probe<<<256, 256, 0, stream>>>((const unsigned short*)d_in[1], in_sizes[1], cnt);
  k_flag<<<1, 1, 0, stream>>>(cnt, flag);

  // ---- convert all float inputs to fp32 (enc h/c straight into hB/cD) ----
  CvtArgs ca;
  float* dsts[20] = { a_traj, hB, cD, a_z, a_Wemb, a_bemb, a_Wihe, a_Whhe, a_bihe,
                      a_bhhe, a_Wihd, a_Whhd, a_bihd, a_bhhd, a_Wout, a_bout,
                      a_Wne, a_bne, a_Watt, a_batt };
  for (int i = 0; i < 20; ++i){
    ca.src[i] = d_in[i];
    ca.dst[i] = dsts[i];
    ca.n[i]   = in_sizes[i];
  }
  k_convert<<<dim3(512, 20), 256, 0, stream>>>(ca, flag);

  // ---- encoder LSTM, 8 steps ----
  for (int t = 0; t < 8; ++t){
    k_embed<<<BB, 64, 0, stream>>>(a_traj + (size_t)t*BB*2, a_Wemb, a_bemb, inp);
    k_gates<<<dim3(1024/64, BB/64), 256, 0, stream>>>(inp, a_Wihe, 64, hB, a_Whhe, EHID,
                                                      a_bihe, a_bhhe, gates, 1024);
    k_lstm<<<(BB*EHID+255)/256, 256, 0, stream>>>(gates, cD, hB, EHID);
  }

  // ---- decoder init ----
  k_concat<<<(BB*DH+255)/256, 256, 0, stream>>>(hB, a_z, hA);
  k_zero_f<<<(BB*DH+255)/256, 256, 0, stream>>>(cD, BB*DH);
  k_copy_f<<<(BB*2+255)/256, 256, 0, stream>>>(a_traj + (size_t)7*BB*2, traj, BB*2);

  float* hcur = hA;
  float* hoth = hB;
  for (int i = 0; i < PRED; ++i){
    k_embed<<<BB, 64, 0, stream>>>(traj, a_Wemb, a_bemb, inp);
    if (i == 4){
      k_sg_emb<<<BB, 64, 0, stream>>>(hcur, a_Wne, a_bne, a_Watt, sself_d, sother_d);
      k_sg_edgecol<<<NG, NN, 0, stream>>>(sself_d, sother_d, a_batt, edge_d);
      k_sg_sym<<<(NG*NN*NN+255)/256, 256, 0, stream>>>(edge_d, esym_d);
      k_sg_dsum<<<(NG*NN+255)/256, 256, 0, stream>>>(esym_d, darr_d);
      k_sg_lsym<<<(NG*NN*NN+255)/256, 256, 0, stream>>>(esym_d, darr_d, Lpack);
      k_sg_eigen<<<NG, 1024, EIG_LDS, stream>>>(Lpack, darr_d, v1_d);
      k_sg_kmeans<<<NG, 256, 0, stream>>>(darr_d, v1_d, labels);
      k_sg_alpha<<<NG, NN, 0, stream>>>(esym_d, labels, Smat);
      k_sg_feat<<<BB, DH, 0, stream>>>(Smat, hcur, hoth);
      float* tmp = hcur; hcur = hoth; hoth = tmp;
    }
    k_gates<<<dim3((4*DH)/64, BB/64), 256, 0, stream>>>(inp, a_Wihd, 64, hcur, a_Whhd, DH,
                                                        a_bihd, a_bhhd, gates, 4*DH);
    k_lstm<<<(BB*DH+255)/256, 256, 0, stream>>>(gates, cD, hcur, DH);
    k_outproj<<<BB, 64, 0, stream>>>(hcur, a_Wout, a_bout, traj, d_out, i, flag);
  }
}

// Round 12
// 2942.563 us; speedup vs baseline: 1.2603x; 1.2603x over previous
//
#include <hip/hip_runtime.h>
#include <hip/hip_bf16.h>

typedef __hip_bfloat16 bf16;

#define NN 192      // nodes per group
#define NG 8        // groups
#define BB 1536     // batch
#define EHID 256
#define DH 320      // decoder hidden
#define PRED 12
#define STRD 193    // padded row stride for the fp32 square (bank-conflict-free cols)

__device__ __forceinline__ float waveSum(float v){
#pragma unroll
  for (int o = 32; o > 0; o >>= 1) v += __shfl_down(v, o);
  return v;
}
__device__ __forceinline__ double waveSumD(double v){
#pragma unroll
  for (int o = 32; o > 0; o >>= 1) v += __shfl_down(v, o);
  return v;
}

__device__ __forceinline__ double blockSumD(double v, double* red){
  int lane = threadIdx.x & 63, wid = threadIdx.x >> 6, nw = (int)blockDim.x >> 6;
  double s = waveSumD(v);
  __syncthreads();
  if (lane == 0) red[wid] = s;
  __syncthreads();
  if (wid == 0){
    double t = (lane < nw) ? red[lane] : 0.0;
    t = waveSumD(t);
    if (lane == 0) red[0] = t;
  }
  __syncthreads();
  return red[0];
}

// ---------------- dtype probe + conversion ----------------

__global__ void k_zero_int(int* __restrict__ p, int n){
  int i = blockIdx.x*blockDim.x + threadIdx.x;
  if (i < n) p[i] = 0;
}
__global__ void k_zero_f(float* __restrict__ p, int n){
  int i = blockIdx.x*blockDim.x + threadIdx.x;
  if (i < n) p[i] = 0.f;
}

__global__ void k_probe(const unsigned short* __restrict__ src, int n, int* __restrict__ cnt){
  int tid = blockIdx.x*blockDim.x + threadIdx.x;
  int stride = gridDim.x*blockDim.x;
  int bad = 0;
  for (int j = tid; j < n; j += stride){
    float v = __uint_as_float(((unsigned int)src[j]) << 16);
    if (!(fabsf(v) < 100.f)) bad++;
  }
#pragma unroll
  for (int o = 32; o > 0; o >>= 1) bad += __shfl_down(bad, o);
  if ((threadIdx.x & 63) == 0 && bad > 0) atomicAdd(cnt, bad);
}
__global__ void k_flag(const int* __restrict__ cnt, int* __restrict__ flag){
  *flag = (*cnt > 4096) ? 1 : 0;        // 1 = inputs are fp32, 0 = bf16
}

struct CvtArgs {
  const void* src[20];
  float*      dst[20];
  int         n[20];
};

__global__ void k_convert(CvtArgs a, const int* __restrict__ flag){
  int id = blockIdx.y;
  int n = a.n[id];
  float* d = a.dst[id];
  int t = blockIdx.x*blockDim.x + threadIdx.x;
  int stride = gridDim.x*blockDim.x;
  if (*flag == 0){
    const bf16* s = (const bf16*)a.src[id];
    for (int j = t; j < n; j += stride) d[j] = __bfloat162float(s[j]);
  } else {
    const float* s = (const float*)a.src[id];
    for (int j = t; j < n; j += stride) d[j] = s[j];
  }
}

// ---------------- elementwise / small kernels ----------------

__global__ void k_embed(const float* __restrict__ in, const float* __restrict__ W,
                        const float* __restrict__ b, float* __restrict__ out){
  int r = blockIdx.x, e = threadIdx.x;
  float x = in[r*2], y = in[r*2+1];
  float v = W[e*2]*x + W[e*2+1]*y + b[e];
  out[r*64+e] = v > 0.f ? v : 0.f;
}

__global__ void k_concat(const float* __restrict__ henc, const float* __restrict__ z,
                         float* __restrict__ h){
  int idx = blockIdx.x*blockDim.x + threadIdx.x;
  if (idx >= BB*DH) return;
  int b = idx / DH, j = idx - b*DH;
  h[idx] = (j < EHID) ? henc[b*EHID + j] : z[(b/NN)*64 + (j - EHID)];
}

__global__ void k_copy_f(const float* __restrict__ in, float* __restrict__ dst, int n){
  int i = blockIdx.x*blockDim.x + threadIdx.x;
  if (i < n) dst[i] = in[i];
}

// gates = A1@W1^T + A2@W2^T + b1 + b2 ; M=1536, N,K multiples of 32/64
__global__ __launch_bounds__(256) void k_gates(
    const float* __restrict__ A1, const float* __restrict__ W1, int K1,
    const float* __restrict__ A2, const float* __restrict__ W2, int K2,
    const float* __restrict__ b1, const float* __restrict__ b2,
    float* __restrict__ C, int N){
  __shared__ __align__(16) float As[32][68];
  __shared__ __align__(16) float Ws[32][68];
  int tid = threadIdx.x;
  int tx = tid & 15, ty = tid >> 4;
  int n0 = blockIdx.x * 64, m0 = blockIdx.y * 64;
  float acc[4][4] = {};
  for (int ph = 0; ph < 2; ++ph){
    const float* A = ph ? A2 : A1;
    const float* W = ph ? W2 : W1;
    int K = ph ? K2 : K1;
    for (int k0 = 0; k0 < K; k0 += 32){
      {
        int am = tid >> 2, ak = (tid & 3) * 8;
        const float* srcA = A + (size_t)(m0+am)*K + k0 + ak;
        float4 f0 = *(const float4*)(srcA);
        float4 f1 = *(const float4*)(srcA+4);
        As[ak+0][am]=f0.x; As[ak+1][am]=f0.y; As[ak+2][am]=f0.z; As[ak+3][am]=f0.w;
        As[ak+4][am]=f1.x; As[ak+5][am]=f1.y; As[ak+6][am]=f1.z; As[ak+7][am]=f1.w;
        const float* srcW = W + (size_t)(n0+am)*K + k0 + ak;
        float4 w0 = *(const float4*)(srcW);
        float4 w1 = *(const float4*)(srcW+4);
        Ws[ak+0][am]=w0.x; Ws[ak+1][am]=w0.y; Ws[ak+2][am]=w0.z; Ws[ak+3][am]=w0.w;
        Ws[ak+4][am]=w1.x; Ws[ak+5][am]=w1.y; Ws[ak+6][am]=w1.z; Ws[ak+7][am]=w1.w;
      }
      __syncthreads();
#pragma unroll
      for (int k = 0; k < 32; ++k){
        float4 a0 = *(const float4*)&As[k][ty*4];
        float4 b0 = *(const float4*)&Ws[k][tx*4];
        float av[4] = {a0.x, a0.y, a0.z, a0.w};
        float bv[4] = {b0.x, b0.y, b0.z, b0.w};
#pragma unroll
        for (int i = 0; i < 4; ++i)
#pragma unroll
          for (int j = 0; j < 4; ++j)
            acc[i][j] += av[i]*bv[j];
      }
      __syncthreads();
    }
  }
  float bs[4];
#pragma unroll
  for (int j = 0; j < 4; ++j){
    int col = n0 + tx*4 + j;
    bs[j] = b1[col] + b2[col];
  }
#pragma unroll
  for (int i = 0; i < 4; ++i){
    int row = m0 + ty*4 + i;
    float4 v;
    v.x = acc[i][0] + bs[0]; v.y = acc[i][1] + bs[1];
    v.z = acc[i][2] + bs[2]; v.w = acc[i][3] + bs[3];
    *(float4*)&C[(size_t)row*N + n0 + tx*4] = v;
  }
}

__global__ void k_lstm(const float* __restrict__ gates, float* __restrict__ c,
                       float* __restrict__ h, int H){
  int idx = blockIdx.x*blockDim.x + threadIdx.x;
  if (idx >= BB*H) return;
  int b = idx / H, j = idx - b*H;
  const float* g = gates + (size_t)b*4*H;
  float gi = g[j], gf = g[H+j], gg = g[2*H+j], go = g[3*H+j];
  float si = 1.f/(1.f+expf(-gi));
  float sf = 1.f/(1.f+expf(-gf));
  float so = 1.f/(1.f+expf(-go));
  float cc = sf*c[idx] + si*tanhf(gg);
  c[idx] = cc;
  h[idx] = so*tanhf(cc);
}

// h(1536x320) -> traj(1536x2) fp32 + output slice `step` (fp32 or bf16 per flag)
__global__ void k_outproj(const float* __restrict__ h, const float* __restrict__ W,
                          const float* __restrict__ bo, float* __restrict__ traj,
                          void* __restrict__ outbase, int step, const int* __restrict__ flag){
  int b = blockIdx.x, lane = threadIdx.x;
  const float* hb = h + (size_t)b*DH;
  float a0 = 0.f, a1 = 0.f;
  for (int k = lane; k < DH; k += 64){
    float hv = hb[k];
    a0 += hv*W[k];
    a1 += hv*W[DH+k];
  }
  a0 = waveSum(a0); a1 = waveSum(a1);
  if (lane == 0){
    a0 += bo[0]; a1 += bo[1];
    traj[b*2] = a0; traj[b*2+1] = a1;
    size_t idx = (size_t)step*BB*2 + (size_t)b*2;
    if (*flag == 0){
      bf16* o = (bf16*)outbase;
      o[idx] = __float2bfloat16(a0); o[idx+1] = __float2bfloat16(a1);
    } else {
      float* o = (float*)outbase;
      o[idx] = a0; o[idx+1] = a1;
    }
  }
}

// ---------------- signed-graph kernels ----------------

__global__ void k_sg_emb(const float* __restrict__ h, const float* __restrict__ Wne,
                         const float* __restrict__ bne, const float* __restrict__ Watt,
                         double* __restrict__ sself, double* __restrict__ sother){
  int node = blockIdx.x, e = threadIdx.x;
  const float* hb = h + (size_t)node*DH;
  double acc = (double)bne[e];
  for (int k = 0; k < DH; ++k) acc += (double)hb[k]*(double)Wne[e*DH+k];
  double po = acc * (double)Watt[e];       // a_other = W_att[0, :64]
  double ps = acc * (double)Watt[64+e];    // a_self  = W_att[0, 64:]
  po = waveSumD(po); ps = waveSumD(ps);
  if (e == 0){ sother[node] = po; sself[node] = ps; }
}

__global__ void k_sg_edgecol(const double* __restrict__ sself, const double* __restrict__ sother,
                             const float* __restrict__ batt, double* __restrict__ edge){
  int g = blockIdx.x, j = threadIdx.x;
  const double* ss = sself + g*NN;
  double bb = (double)batt[0];
  double sj = sother[g*NN + j];
  double m = -1e300;
  for (int i = 0; i < NN; ++i){
    double e = ss[i] + sj + bb; e = e > 0.0 ? e : 0.2*e;
    m = fmax(m, e);
  }
  double sum = 0.0;
  for (int i = 0; i < NN; ++i){
    double e = ss[i] + sj + bb; e = e > 0.0 ? e : 0.2*e;
    sum += exp(e - m);
  }
  double* E = edge + (size_t)g*NN*NN;
  for (int i = 0; i < NN; ++i){
    double e = ss[i] + sj + bb; e = e > 0.0 ? e : 0.2*e;
    E[i*NN + j] = exp(e - m)/sum;
  }
}

__global__ void k_sg_sym(const double* __restrict__ edge, double* __restrict__ esym){
  int idx = blockIdx.x*blockDim.x + threadIdx.x;
  if (idx >= NG*NN*NN) return;
  int g = idx / (NN*NN), r = idx - g*NN*NN;
  int i = r / NN, j = r - i*NN;
  const double* E = edge + (size_t)g*NN*NN;
  esym[idx] = (i <= j) ? E[i*NN + j] : E[j*NN + i];
}

__global__ void k_sg_dsum(const double* __restrict__ esym, double* __restrict__ darr){
  int i = blockIdx.x*blockDim.x + threadIdx.x;
  if (i >= NG*NN) return;
  int g = i / NN, li = i - g*NN;
  const double* E = esym + (size_t)g*NN*NN + (size_t)li*NN;
  double s = 0.0;
  for (int j = 0; j < NN; ++j) s += E[j];
  darr[i] = fmax(s, 1e-300);
}

// L_sym as FULL fp32 square, padded row stride STRD
__global__ void k_sg_lsym(const double* __restrict__ esym, const double* __restrict__ darr,
                          float* __restrict__ Afull){
  int idx = blockIdx.x*blockDim.x + threadIdx.x;
  if (idx >= NG*NN*NN) return;
  int g = idx / (NN*NN), r = idx - g*NN*NN;
  int i = r / NN, j = r - i*NN;
  double w = esym[idx];
  double lij = (i == j) ? (darr[g*NN+i] - w) : (-w);
  Afull[(size_t)g*NN*STRD + i*STRD + j] =
      (float)(lij / (sqrt(darr[g*NN+i])*sqrt(darr[g*NN+j])));
}

// LDS-resident FULL-SQUARE fp32 Householder tridiag (1024 thr, 16 waves,
// 4-row-batched wave-per-row). RACE-FIXED: raw column stays in vv (read-only
// after B1); scaled reflector built in separate uu. + fp64 Sturm bisection +
// fp64 serial inverse iteration + mixed back-transform + Gram-Schmidt.
// dynamic LDS = 160768 B.
__global__ __launch_bounds__(1024) void k_sg_eigen(const float* __restrict__ Afull,
                                                   const double* __restrict__ darr,
                                                   double* __restrict__ v1out){
  extern __shared__ unsigned char ldsraw[];
  float*  A     = (float*)ldsraw;                       // NN*STRD fp32 (148224 B)
  double* dd    = (double*)(ldsraw + 148224);           // NN
  double* ee    = dd + NN;                              // NN
  double* yv    = ee + NN;                              // NN
  double* lu_d  = yv + NN;                              // NN
  double* lu_du = lu_d + NN;                            // NN
  double* lu_du2= lu_du + NN;                           // NN
  double* redA  = lu_du2 + NN;                          // 16
  double* redB  = redA + 16;                            // 16
  float*  vv    = (float*)(redB + 16);                  // NN fp32 (raw column)
  float*  pp    = vv + NN;                              // NN fp32
  float*  uu    = pp + NN;                              // NN fp32 (scaled reflector)
  int*    lu_piv= (int*)(uu + NN);                      // NN int
  double* lu_dl = (double*)vv;                          // alias (vv+pp = 1536 B, dead in LU)

  int g = blockIdx.x, tid = threadIdx.x;
  int lane = tid & 63, wid = tid >> 6;  // 16 waves

  const float* src = Afull + (size_t)g*NN*STRD;
  for (int t = tid; t < NN*STRD; t += 1024) A[t] = src[t];
  __syncthreads();

  // ---- tridiagonalization (fp32 matrix, fp64 scalars) ----
  for (int k = 0; k < NN-2; ++k){
    int m = NN-1-k;                        // trailing rows i = k+1..NN-1
    // column k -> vv (RAW, never modified this step), sigma partials
    float part = 0.f;
    if (tid < m){
      int i = k+1+tid;
      float x = A[i*STRD + k];
      vv[i] = x;
      if (i > k+1) part = x*x;
    }
    part = waveSum(part);
    if (lane == 0) redA[wid] = (double)part;
    __syncthreads();                                   // B1
    double sigma = 0.0;
#pragma unroll
    for (int w = 0; w < 16; ++w) sigma += redA[w];
    double alpha = (double)vv[k+1];                    // ordered vs pre-B1 write
    double beta, tau, scale;
    if (sigma <= 1e-30){ tau = 0.0; beta = alpha; scale = 0.0; }
    else {
      beta = -copysign(sqrt(alpha*alpha + sigma), alpha);
      tau = (beta - alpha)/beta;
      scale = 1.0/(alpha - beta);
    }
    float tau_f = (float)tau, scale_f = (float)scale;
    if (tid == 0){
      dd[k] = (double)A[k*STRD + k];
      ee[k] = beta;
      A[k*STRD + k] = tau_f;               // stash tau on dead diagonal slot
    }
    if (tau != 0.0){                        // block-uniform branch
      // build u in uu (u[k+1]=1, u[i]=v_i*scale); store into dead column k
      if (tid == 0) uu[k+1] = 1.0f;
      if (tid < m-1){
        int i = k+2+tid;
        float u = vv[i]*scale_f;
        uu[i] = u;
        A[i*STRD + k] = u;                  // for back-transform
      }
      __syncthreads();                                 // B2: u ready
      // matvec p = tau * A * u (4-row-batched wave-per-row, contiguous rows)
      for (int base = 0; base < m; base += 64){
        int r0 = base + wid;
        int i0 = k+1+r0, i1 = i0+16, i2 = i0+32, i3 = i0+48;
        bool c0 = r0 < m, c1 = r0+16 < m, c2 = r0+32 < m, c3 = r0+48 < m;
        int b0 = i0*STRD, b1 = i1*STRD, b2 = i2*STRD, b3 = i3*STRD;
        float s0=0.f, s1=0.f, s2=0.f, s3=0.f;
        for (int j = k+1+lane; j < NN; j += 64){
          float uj = uu[j];
          if (c0) s0 += A[b0+j]*uj;
          if (c1) s1 += A[b1+j]*uj;
          if (c2) s2 += A[b2+j]*uj;
          if (c3) s3 += A[b3+j]*uj;
        }
#pragma unroll
        for (int o = 32; o > 0; o >>= 1){
          s0 += __shfl_down(s0, o); s1 += __shfl_down(s1, o);
          s2 += __shfl_down(s2, o); s3 += __shfl_down(s3, o);
        }
        if (lane == 0){
          if (c0) pp[i0] = tau_f*s0;
          if (c1) pp[i1] = tau_f*s1;
          if (c2) pp[i2] = tau_f*s2;
          if (c3) pp[i3] = tau_f*s3;
        }
      }
      __syncthreads();                                 // B3: p ready
      // vtp = u . p
      float pv = 0.f;
      if (tid < m){ int i = k+1+tid; pv = uu[i]*pp[i]; }
      pv = waveSum(pv);
      if (lane == 0) redB[wid] = (double)pv;
      __syncthreads();                                 // B4
      double vtp = 0.0;
#pragma unroll
      for (int w = 0; w < 16; ++w) vtp += redB[w];
      float Kc_f = (float)(0.5*tau*vtp);
      // w = p - Kc*u (in place)
      if (tid < m){ int i = k+1+tid; pp[i] -= Kc_f*uu[i]; }
      __syncthreads();                                 // B5: w ready
      // rank-2 on FULL trailing square: A[i][j] -= u_i w_j + w_i u_j
      for (int base = 0; base < m; base += 64){
        int r0 = base + wid;
        int i0 = k+1+r0, i1 = i0+16, i2 = i0+32, i3 = i0+48;
        bool c0 = r0 < m, c1 = r0+16 < m, c2 = r0+32 < m, c3 = r0+48 < m;
        int b0 = i0*STRD, b1 = i1*STRD, b2 = i2*STRD, b3 = i3*STRD;
        float u0 = c0 ? uu[i0] : 0.f, w0 = c0 ? pp[i0] : 0.f;
        float u1 = c1 ? uu[i1] : 0.f, w1 = c1 ? pp[i1] : 0.f;
        float u2 = c2 ? uu[i2] : 0.f, w2 = c2 ? pp[i2] : 0.f;
        float u3 = c3 ? uu[i3] : 0.f, w3 = c3 ? pp[i3] : 0.f;
        for (int j = k+1+lane; j < NN; j += 64){
          float uj = uu[j], wj = pp[j];
          if (c0) A[b0+j] -= u0*wj + w0*uj;
          if (c1) A[b1+j] -= u1*wj + w1*uj;
          if (c2) A[b2+j] -= u2*wj + w2*uj;
          if (c3) A[b3+j] -= u3*wj + w3*uj;
        }
      }
      __syncthreads();                                 // B6: A ready for next k
    } else {
      __syncthreads();                                 // order redA reuse (rare path)
    }
  }
  if (tid == 0){
    dd[NN-2] = (double)A[(NN-2)*STRD + (NN-2)];
    ee[NN-2] = (double)A[(NN-1)*STRD + (NN-2)];
    dd[NN-1] = (double)A[(NN-1)*STRD + (NN-1)];
  }
  __syncthreads();

  // ---- bisection (wave 0) + serial LU/inverse-iteration (lane 0), fp64 ----
  if (wid == 0){
    double mn = 1e300, mx = -1e300;
    for (int i = lane; i < NN; i += 64){
      double r = (i > 0 ? fabs(ee[i-1]) : 0.0) + (i < NN-1 ? fabs(ee[i]) : 0.0);
      mn = fmin(mn, dd[i]-r); mx = fmax(mx, dd[i]+r);
    }
#pragma unroll
    for (int o = 32; o > 0; o >>= 1){
      mn = fmin(mn, __shfl_down(mn, o));
      mx = fmax(mx, __shfl_down(mx, o));
    }
    mn = __shfl(mn, 0); mx = __shfl(mx, 0);
    double lo = mn - 1e-8 - 1e-9*fabs(mn);
    double hi = mx + 1e-8 + 1e-9*fabs(mx);
    for (int it = 0; it < 10; ++it){
      double lam = lo + (hi-lo)*((double)(lane+1)/65.0);
      int cnt = 0;
      double q = dd[0] - lam;
      if (q < 0.0) cnt++;
      for (int i2 = 1; i2 < NN; ++i2){
        double den = q;
        if (fabs(den) < 1e-280) den = (den < 0.0) ? -1e-280 : 1e-280;
        q = dd[i2] - lam - ee[i2-1]*ee[i2-1]/den;
        if (q < 0.0) cnt++;
      }
      unsigned long long bal = __ballot(cnt >= 2);
      if (bal == 0ull){
        lo = lo + (hi-lo)*(64.0/65.0);
      } else {
        int j0 = __ffsll(bal) - 1;
        double nl = lo + (hi-lo)*((double)j0/65.0);
        double nh = lo + (hi-lo)*((double)(j0+1)/65.0);
        lo = nl; hi = nh;
      }
    }
    double lam1 = 0.5*(lo+hi);

    if (lane == 0){
      for (int i = 0; i < NN; ++i) lu_d[i] = dd[i] - lam1;
      for (int i = 0; i < NN-1; ++i){ lu_dl[i] = ee[i]; lu_du[i] = ee[i]; }
      for (int i = 0; i < NN-2; ++i) lu_du2[i] = 0.0;
      for (int i = 0; i < NN-1; ++i){
        if (fabs(lu_d[i]) >= fabs(lu_dl[i])){
          double di = lu_d[i];
          if (fabs(di) < 1e-30){ di = (di < 0.0) ? -1e-30 : 1e-30; lu_d[i] = di; }
          double fact = lu_dl[i]/di;
          lu_dl[i] = fact;
          lu_d[i+1] -= fact*lu_du[i];
          lu_piv[i] = 0;
        } else {
          double fact = lu_d[i]/lu_dl[i];
          lu_d[i] = lu_dl[i];
          double tmp = lu_d[i+1];
          lu_d[i+1] = lu_du[i] - fact*tmp;
          if (i < NN-2){ lu_du2[i] = lu_du[i+1]; lu_du[i+1] = -fact*lu_du[i+1]; }
          lu_du[i] = tmp;
          lu_dl[i] = fact;
          lu_piv[i] = 1;
        }
      }
      if (fabs(lu_d[NN-1]) < 1e-30)
        lu_d[NN-1] = (lu_d[NN-1] < 0.0) ? -1e-30 : 1e-30;
      for (int i = 0; i < NN; ++i) yv[i] = 1.0 + 0.001*(double)((i*37)%29);
      for (int round = 0; round < 2; ++round){
        for (int i = 0; i < NN-1; ++i){
          if (lu_piv[i] == 0){
            yv[i+1] -= lu_dl[i]*yv[i];
          } else {
            double t = yv[i]; yv[i] = yv[i+1]; yv[i+1] = t - lu_dl[i]*yv[i];
          }
        }
        double mx1 = 0.0;
        for (int i = 0; i < NN; ++i) mx1 = fmax(mx1, fabs(yv[i]));
        double inv1 = (mx1 > 0.0 && isfinite(mx1)) ? 1.0/mx1 : 1.0;
        for (int i = 0; i < NN; ++i) yv[i] *= inv1;
        yv[NN-1] = yv[NN-1]/lu_d[NN-1];
        yv[NN-2] = (yv[NN-2] - lu_du[NN-2]*yv[NN-1])/lu_d[NN-2];
        for (int i = NN-3; i >= 0; --i)
          yv[i] = (yv[i] - lu_du[i]*yv[i+1] - lu_du2[i]*yv[i+2])/lu_d[i];
        double mxv = 0.0;
        for (int i = 0; i < NN; ++i) mxv = fmax(mxv, fabs(yv[i]));
        double inv = (mxv > 0.0 && isfinite(mxv)) ? 1.0/mxv : 1.0;
        for (int i = 0; i < NN; ++i){
          double val = yv[i]*inv;
          if (!isfinite(val)) val = 0.0;
          yv[i] = val;
        }
      }
    }
  }
  __syncthreads();                       // yv ready

  // ---- back-transform: y <- H_0 ... H_{n-3} y  (u fp32, accumulate fp64) ----
  for (int k = NN-3; k >= 0; --k){
    double tau = (double)A[k*STRD + k];
    if (tau != 0.0){                     // block-uniform
      int i = k+1+tid;
      double ui = 0.0, part = 0.0;
      if (tid < NN-1-k){
        ui = (tid == 0) ? 1.0 : (double)A[i*STRD + k];
        part = ui*yv[i];
      }
      part = waveSumD(part);
      if (lane == 0) redA[wid] = part;
      __syncthreads();
      double dot = 0.0;
#pragma unroll
      for (int w = 0; w < 16; ++w) dot += redA[w];
      double s = tau*dot;
      if (tid < NN-1-k) yv[i] -= s*ui;
      __syncthreads();
    }
  }

  // ---- Gram-Schmidt against v0 = sqrt(d) + normalize (fp64) ----
  {
    double pd = 0.0, pn2 = 0.0;
    if (tid < NN){
      double sd = sqrt(darr[g*NN + tid]);
      pd = sd*yv[tid];
      pn2 = darr[g*NN + tid];
    }
    pd = waveSumD(pd); pn2 = waveSumD(pn2);
    if (lane == 0){ redA[wid] = pd; redB[wid] = pn2; }
    __syncthreads();
    double dot = 0.0, n2 = 0.0;
#pragma unroll
    for (int w = 0; w < 16; ++w){ dot += redA[w]; n2 += redB[w]; }
    double coef = dot/fmax(n2, 1e-300);
    if (tid < NN) yv[tid] -= coef*sqrt(darr[g*NN + tid]);
    __syncthreads();
    double pn = 0.0;
    if (tid < NN) pn = yv[tid]*yv[tid];
    pn = waveSumD(pn);
    if (lane == 0) redA[wid] = pn;
    __syncthreads();
    double s2 = 0.0;
#pragma unroll
    for (int w = 0; w < 16; ++w) s2 += redA[w];
    double nrm = sqrt(s2);
    double inv = (nrm > 0.0 && isfinite(nrm)) ? 1.0/nrm : 0.0;
    if (tid < NN){
      double val = yv[tid]*inv;
      if (!isfinite(val)) val = 0.0;
      v1out[g*NN + tid] = val;
    }
  }
}

// kmeans on row-normalized [sqrt(d)/||.||, v1]  (fp64)
__global__ __launch_bounds__(256) void k_sg_kmeans(const double* __restrict__ darr,
                                                   const double* __restrict__ v1,
                                                   int* __restrict__ labels){
  __shared__ double px[NN], py[NN], cx[96], cy[96];
  __shared__ int lab[NN];
  __shared__ double red[16];
  int g = blockIdx.x, tid = threadIdx.x;
  double part = 0.0;
  for (int i = tid; i < NN; i += 256) part += darr[g*NN + i];
  double sumd = blockSumD(part, red);
  double invn = 1.0/sqrt(fmax(sumd, 1e-300));
  for (int i = tid; i < NN; i += 256){
    double h0 = sqrt(darr[g*NN + i])*invn;
    double h1 = v1[g*NN + i];
    double rn = sqrt(h0*h0 + h1*h1);
    double ax = h0/rn, ay = h1/rn;
    if (!isfinite(ax)) ax = 0.0;
    if (!isfinite(ay)) ay = 0.0;
    px[i] = ax; py[i] = ay;
  }
  __syncthreads();
  if (tid < 96){ cx[tid] = px[tid]; cy[tid] = py[tid]; }
  __syncthreads();
  for (int it = 0; it <= 10; ++it){
    if (tid < NN){
      double bx = px[tid], by = py[tid];
      double best = 1e300; int bi = 0;
      for (int a = 0; a < 96; ++a){
        double dx = bx - cx[a], dy = by - cy[a];
        double d2 = dx*dx + dy*dy;
        if (d2 < best){ best = d2; bi = a; }
      }
      lab[tid] = bi;
    }
    __syncthreads();
    if (it == 10) break;
    if (tid < 96){
      int c = 0; double sx = 0.0, sy = 0.0;
      for (int i = 0; i < NN; ++i){
        if (lab[i] == tid){ c++; sx += px[i]; sy += py[i]; }
      }
      if (c > 0){ cx[tid] = sx/(double)c; cy[tid] = sy/(double)c; }
      else      { cx[tid] = px[tid];      cy[tid] = py[tid]; }
    }
    __syncthreads();
  }
  if (tid < NN) labels[g*NN + tid] = lab[tid];
}

// S = pos_alpha + neg_alpha (fp64 in, fp32 out)
__global__ void k_sg_alpha(const double* __restrict__ esym, const int* __restrict__ labels,
                           float* __restrict__ S){
  __shared__ int lbs[NN];
  int g = blockIdx.x, j = threadIdx.x;
  if (j < NN) lbs[j] = labels[g*NN + j];
  __syncthreads();
  const double* E = esym + (size_t)g*NN*NN;
  const double NEG = -100000000.0;
  int lj = lbs[j];
  double mp = -1e300, mn = -1e300;
  for (int i = 0; i < NN; ++i){
    double w = E[i*NN + j];
    bool sm = (lbs[i] == lj);
    double vp = sm ? w : w*NEG; vp = vp > 0.0 ? vp : 0.2*vp;
    double vn = sm ? w*NEG : w; vn = vn > 0.0 ? vn : 0.2*vn;
    mp = fmax(mp, vp); mn = fmax(mn, vn);
  }
  double sp = 0.0, sn = 0.0;
  for (int i = 0; i < NN; ++i){
    double w = E[i*NN + j];
    bool sm = (lbs[i] == lj);
    double vp = sm ? w : w*NEG; vp = vp > 0.0 ? vp : 0.2*vp;
    double vn = sm ? w*NEG : w; vn = vn > 0.0 ? vn : 0.2*vn;
    sp += exp(vp - mp); sn += exp(vn - mn);
  }
  float* So = S + (size_t)g*NN*NN;
  for (int i = 0; i < NN; ++i){
    double w = E[i*NN + j];
    bool sm = (lbs[i] == lj);
    double vp = sm ? w : w*NEG; vp = vp > 0.0 ? vp : 0.2*vp;
    double vn = sm ? w*NEG : w; vn = vn > 0.0 ? vn : 0.2*vn;
    So[i*NN + j] = (float)(exp(vp - mp)/sp + exp(vn - mn)/sn);
  }
}

// h_out[i,:] = sum_j S[i,j] * relu(h_in[j,:]) per group
__global__ __launch_bounds__(320) void k_sg_feat(const float* __restrict__ S,
                                                 const float* __restrict__ hin,
                                                 float* __restrict__ hout){
  int r = blockIdx.x;
  int g = r / NN, li = r - g*NN;
  int dh = threadIdx.x;
  const float* Srow = S + (size_t)g*NN*NN + (size_t)li*NN;
  const float* hb = hin + (size_t)g*NN*DH;
  float acc = 0.f;
  for (int j = 0; j < NN; ++j){
    float w = Srow[j];
    float x = hb[(size_t)j*DH + dh];
    acc += w*(x > 0.f ? x : 0.f);
  }
  hout[(size_t)r*DH + dh] = acc;
}

// ---------------- host ----------------

extern "C" void kernel_launch(void* const* d_in, const int* in_sizes, int n_in,
                              void* d_out, int out_size, void* d_ws, size_t ws_size,
                              hipStream_t stream){
  (void)n_in; (void)out_size; (void)ws_size;

  // ---- workspace layout (float offsets) ----
  float* ws = (float*)d_ws;
  float* inp   = ws;                       // 98304
  float* gates = ws + 98304;               // 1966080
  float* hA    = ws + 2064384;             // 491520
  float* hB    = ws + 2555904;             // 491520
  float* cD    = ws + 3047424;             // 491520
  float* traj  = ws + 3538944;             // 3072
  double* sself_d  = (double*)(ws + 3542016);  // 3072 f
  double* sother_d = (double*)(ws + 3545088);  // 3072 f
  double* darr_d   = (double*)(ws + 3548160);  // 3072 f
  double* v1_d     = (double*)(ws + 3551232);  // 3072 f
  int*    labels   = (int*)(ws + 3554304);     // 1536
  // graph matrices overlay the (dead) gates buffer:
  double* edge_d = (double*)gates;             // 589824 f
  double* esym_d = (double*)(gates + 589824);  // 589824 f
  float*  Afull  = gates + 1179648;            // NG*NN*STRD f = 296448 f
  float*  Smat   = gates;                      // fp32 S reuses edge_d space (dead by then)
  // fp32 parameter arena:
  float* a_traj = ws + 3555840;            // 61440
  float* a_z    = ws + 3617280;            // 512
  float* a_Wemb = ws + 3617792;            // 128
  float* a_bemb = ws + 3617920;            // 64
  float* a_Wihe = ws + 3617984;            // 65536
  float* a_Whhe = ws + 3683520;            // 262144
  float* a_bihe = ws + 3945664;            // 1024
  float* a_bhhe = ws + 3946688;            // 1024
  float* a_Wihd = ws + 3947712;            // 81920
  float* a_Whhd = ws + 4029632;            // 409600
  float* a_bihd = ws + 4439232;            // 1280
  float* a_bhhd = ws + 4440512;            // 1280
  float* a_Wout = ws + 4441792;            // 640
  float* a_bout = ws + 4442432;            // 64
  float* a_Wne  = ws + 4442496;            // 20480
  float* a_bne  = ws + 4462976;            // 64
  float* a_Watt = ws + 4463040;            // 128
  float* a_batt = ws + 4463168;            // 64
  int* cnt  = (int*)(ws + 4463232);
  int* flag = (int*)(ws + 4463233);        // ~17.0 MiB total

  // allow >64KB dynamic LDS for the eigen kernel (idempotent, host-side)
  const int EIG_LDS = 160768;
  hipFuncSetAttribute((const void*)k_sg_eigen,
                      hipFuncAttributeMaxDynamicSharedMemorySize, EIG_LDS);

  // ---- dtype probe ----
  k_zero_int<<<1, 64, 0, stream>>>(cnt, 2);
  k_probe<<<256, 256, 0, stream>>>((const unsigned short*)d_in[1], in_sizes[1], cnt);
  k_flag<<<1, 1, 0, stream>>>(cnt, flag);

  // ---- convert all float inputs to fp32 (enc h/c straight into hB/cD) ----
  CvtArgs ca;
  float* dsts[20] = { a_traj, hB, cD, a_z, a_Wemb, a_bemb, a_Wihe, a_Whhe, a_bihe,
                      a_bhhe, a_Wihd, a_Whhd, a_bihd, a_bhhd, a_Wout, a_bout,
                      a_Wne, a_bne, a_Watt, a_batt };
  for (int i = 0; i < 20; ++i){
    ca.src[i] = d_in[i];
    ca.dst[i] = dsts[i];
    ca.n[i]   = in_sizes[i];
  }
  k_convert<<<dim3(512, 20), 256, 0, stream>>>(ca, flag);

  // ---- encoder LSTM, 8 steps ----
  for (int t = 0; t < 8; ++t){
    k_embed<<<BB, 64, 0, stream>>>(a_traj + (size_t)t*BB*2, a_Wemb, a_bemb, inp);
    k_gates<<<dim3(1024/64, BB/64), 256, 0, stream>>>(inp, a_Wihe, 64, hB, a_Whhe, EHID,
                                                      a_bihe, a_bhhe, gates, 1024);
    k_lstm<<<(BB*EHID+255)/256, 256, 0, stream>>>(gates, cD, hB, EHID);
  }

  // ---- decoder init ----
  k_concat<<<(BB*DH+255)/256, 256, 0, stream>>>(hB, a_z, hA);
  k_zero_f<<<(BB*DH+255)/256, 256, 0, stream>>>(cD, BB*DH);
  k_copy_f<<<(BB*2+255)/256, 256, 0, stream>>>(a_traj + (size_t)7*BB*2, traj, BB*2);

  float* hcur = hA;
  float* hoth = hB;
  for (int i = 0; i < PRED; ++i){
    k_embed<<<BB, 64, 0, stream>>>(traj, a_Wemb, a_bemb, inp);
    if (i == 4){
      k_sg_emb<<<BB, 64, 0, stream>>>(hcur, a_Wne, a_bne, a_Watt, sself_d, sother_d);
      k_sg_edgecol<<<NG, NN, 0, stream>>>(sself_d, sother_d, a_batt, edge_d);
      k_sg_sym<<<(NG*NN*NN+255)/256, 256, 0, stream>>>(edge_d, esym_d);
      k_sg_dsum<<<(NG*NN+255)/256, 256, 0, stream>>>(esym_d, darr_d);
      k_sg_lsym<<<(NG*NN*NN+255)/256, 256, 0, stream>>>(esym_d, darr_d, Afull);
      k_sg_eigen<<<NG, 1024, EIG_LDS, stream>>>(Afull, darr_d, v1_d);
      k_sg_kmeans<<<NG, 256, 0, stream>>>(darr_d, v1_d, labels);
      k_sg_alpha<<<NG, NN, 0, stream>>>(esym_d, labels, Smat);
      k_sg_feat<<<BB, DH, 0, stream>>>(Smat, hcur, hoth);
      float* tmp = hcur; hcur = hoth; hoth = tmp;
    }
    k_gates<<<dim3((4*DH)/64, BB/64), 256, 0, stream>>>(inp, a_Wihd, 64, hcur, a_Whhd, DH,
                                                        a_bihd, a_bhhd, gates, 4*DH);
    k_lstm<<<(BB*DH+255)/256, 256, 0, stream>>>(gates, cD, hcur, DH);
    k_outproj<<<BB, 64, 0, stream>>>(hcur, a_Wout, a_bout, traj, d_out, i, flag);
  }
}